// Round 17
// baseline (347.988 us; speedup 1.0000x reference)
//
#include <hip/hip_runtime.h>

#define D 256
#define SB 1024
typedef __attribute__((ext_vector_type(8))) short short8;
typedef __attribute__((ext_vector_type(4))) float floatx4;

__device__ __forceinline__ unsigned short f2bf(float f) {
  unsigned int u = __float_as_uint(f);
  u = (u + 0x7FFF + ((u >> 16) & 1)) >> 16;   // RNE
  return (unsigned short)u;
}
__device__ __forceinline__ float bf2f(unsigned short h) {
  return __uint_as_float(((unsigned int)h) << 16);
}

// async global->LDS, 16B per lane; LDS dest = wave-uniform base + lane*16
__device__ __forceinline__ void glds16(const void* g, void* l) {
  __builtin_amdgcn_global_load_lds(
      (const __attribute__((address_space(1))) unsigned int*)g,
      (__attribute__((address_space(3))) unsigned int*)l, 16, 0, 0);
}

// ---------------- fused independent setup: zero | bounds | cvt | cvt_w x2 --
// r27: table cvt x8 (G13). r14: weight cvt x4 (ushort4 stores).
__global__ __launch_bounds__(256) void k_setup(
    int* __restrict__ cur, int RN,
    const int* __restrict__ batch, int* __restrict__ gstart, int N, int G,
    const float* __restrict__ table, unsigned short* __restrict__ tableb, int TN,
    const float* __restrict__ root1, const float* __restrict__ W1,
    const float* __restrict__ root2, const float* __restrict__ W2,
    unsigned short* __restrict__ wb, int* __restrict__ zrowi,
    int g0, int g1, int g2, int g3) {
  int b = blockIdx.x, t = threadIdx.x;
  if (b < g0) {                       // zero cur, int4 per thread
    int i = b * 1024 + t * 4;
#pragma unroll
    for (int j = 0; j < 4; j++) if (i + j < RN) cur[i + j] = 0;
    if (b == 0 && t < 128) zrowi[t] = 0;   // 512B zero feature row
  } else if (b < g1) {                // graph bounds
    int i = (b - g0) * 256 + t;
    if (i >= N) return;
    int bb = batch[i];
    if (i == 0) { for (int g = 0; g <= bb; g++) gstart[g] = 0; }
    else { int pb = batch[i - 1]; for (int g = pb + 1; g <= bb; g++) gstart[g] = i; }
    if (i == N - 1) { for (int g = bb + 1; g <= G; g++) gstart[g] = N; }
  } else if (b < g2) {                // table fp32 -> bf16, 8 elems/thread
    int i = ((b - g1) * 256 + t) * 8;
    if (i < TN) {
      float4 f0 = *(const float4*)(table + i);
      float4 f1 = *(const float4*)(table + i + 4);
      ushort4 o0, o1;
      o0.x = f2bf(f0.x); o0.y = f2bf(f0.y); o0.z = f2bf(f0.z); o0.w = f2bf(f0.w);
      o1.x = f2bf(f1.x); o1.y = f2bf(f1.y); o1.z = f2bf(f1.z); o1.w = f2bf(f1.w);
      *(ushort4*)(tableb + i) = o0;
      *(ushort4*)(tableb + i + 4) = o1;
    }
  } else {                            // weights -> bf16 transposed, 4/thread
    int layer = (b < g3) ? 0 : 1;
    int idx4 = ((b - (layer ? g3 : g2)) * 256 + t) * 4;  // 0..262140, step 4
    int mat = idx4 >> 16, rem = idx4 & 65535;
    int n = rem >> 8, k0 = rem & 255;
    const float* root = layer ? root2 : root1;
    const float* W = layer ? W2 : W1;
    const float* s = (mat == 0) ? root : (W + (size_t)(mat - 1) * 65536);
    ushort4 o;
    o.x = f2bf(s[(k0 + 0) * 256 + n]);
    o.y = f2bf(s[(k0 + 1) * 256 + n]);
    o.z = f2bf(s[(k0 + 2) * 256 + n]);
    o.w = f2bf(s[(k0 + 3) * 256 + n]);
    *(ushort4*)(wb + (size_t)layer * 4 * 65536 + idx4) = o;
  }
}

// ---------------- per-(relation,node) in-edge counts ----------------
__global__ __launch_bounds__(256) void k_count_i(const int* __restrict__ dst,
    const int* __restrict__ et, int* __restrict__ cnt, int E, int N) {
  int e = blockIdx.x * 256 + threadIdx.x;
  if (e >= E) return;
  atomicAdd(&cnt[et[e] * N + dst[e]], 1);
}

// ---------------- 3-kernel scan chain (proven r11/r14) ----------------
__global__ __launch_bounds__(256) void k_scan1(const int* __restrict__ in,
    int* __restrict__ bsum, int n) {
  __shared__ int s[256];
  int base = blockIdx.x * SB, t = threadIdx.x;
  int a = 0;
#pragma unroll
  for (int j = 0; j < 4; j++) { int i = base + t * 4 + j; if (i < n) a += in[i]; }
  s[t] = a; __syncthreads();
  for (int o = 128; o > 0; o >>= 1) { if (t < o) s[t] += s[t + o]; __syncthreads(); }
  if (t == 0) bsum[blockIdx.x] = s[0];
}

__global__ __launch_bounds__(256) void k_scan2(int* __restrict__ bsum, int nb,
    int* __restrict__ total_out) {
  __shared__ int s[256];
  int t = threadIdx.x;
  int v[4]; int a = 0;
#pragma unroll
  for (int j = 0; j < 4; j++) {
    int i = t * 4 + j;
    v[j] = (i < nb) ? bsum[i] : 0;
    a += v[j];
  }
  s[t] = a; __syncthreads();
  for (int o = 1; o < 256; o <<= 1) {
    int x_ = (t >= o) ? s[t - o] : 0;
    __syncthreads();
    s[t] += x_;
    __syncthreads();
  }
  int excl = (t > 0) ? s[t - 1] : 0;
#pragma unroll
  for (int j = 0; j < 4; j++) {
    int i = t * 4 + j;
    if (i < nb) { bsum[i] = excl; excl += v[j]; }
  }
  if (t == 255) *total_out = s[255];
}

__global__ __launch_bounds__(256) void k_scan3(const int* __restrict__ in,
    const int* __restrict__ bsum, int* __restrict__ off, int* __restrict__ cur,
    int n) {
  __shared__ int s[256];
  int base = blockIdx.x * SB, t = threadIdx.x;
  int v[4]; int a = 0;
#pragma unroll
  for (int j = 0; j < 4; j++) {
    int i = base + t * 4 + j;
    v[j] = (i < n) ? in[i] : 0;
    a += v[j];
  }
  s[t] = a; __syncthreads();
  for (int o = 1; o < 256; o <<= 1) {
    int x_ = (t >= o) ? s[t - o] : 0;
    __syncthreads();
    s[t] += x_;
    __syncthreads();
  }
  int excl = (t > 0 ? s[t - 1] : 0) + bsum[blockIdx.x];
#pragma unroll
  for (int j = 0; j < 4; j++) {
    int i = base + t * 4 + j;
    if (i < n) { off[i] = excl; cur[i] = excl; excl += v[j]; }
  }
}

// CSR placement: esx[pos] = x[src] (L1 row id), ess[pos] = src (L2 row id)
__global__ __launch_bounds__(256) void k_place2(const int* __restrict__ src,
    const int* __restrict__ dst, const int* __restrict__ et,
    const int* __restrict__ x, int* __restrict__ cur,
    int* __restrict__ esx, int* __restrict__ ess, int E, int N) {
  int e = blockIdx.x * 256 + threadIdx.x;
  if (e >= E) return;
  int s = src[e];
  int pos = atomicAdd(&cur[et[e] * N + dst[e]], 1);
  esx[pos] = x[s];
  ess[pos] = s;
}

// ---------------- relation aggregation, 8 ids per wave, MULTI-EDGE ONLY ---
// (L2 only) r6-proven: cnt==0/1 ids not materialized.
__global__ __launch_bounds__(256) void k_agg(const unsigned short* __restrict__ h,
    const int* __restrict__ rows, const int* __restrict__ off,
    unsigned short* __restrict__ out, int RN) {
  const int wave = threadIdx.x >> 6, lane = threadIdx.x & 63;
  const int base = (blockIdx.x * 4 + wave) * 8;
  if (base >= RN) return;

  int lo[8], hi[8];
#pragma unroll
  for (int j = 0; j < 8; j++) {
    int id = base + j;
    lo[j] = (id < RN) ? off[id] : 0;
    hi[j] = (id < RN) ? off[id + 1] : 0;
    if (hi[j] - lo[j] < 2) hi[j] = lo[j];   // skip: handled by GEMM gather
  }

  int r0[8];
#pragma unroll
  for (int j = 0; j < 8; j++)
    r0[j] = (hi[j] > lo[j]) ? rows[lo[j]] : 0;

  ushort4 v0[8];
#pragma unroll
  for (int j = 0; j < 8; j++)
    v0[j] = (hi[j] > lo[j])
        ? *(const ushort4*)(h + (size_t)r0[j] * D + lane * 4)
        : make_ushort4(0, 0, 0, 0);

  float a[8][4];
#pragma unroll
  for (int j = 0; j < 8; j++) {
    a[j][0] = bf2f(v0[j].x); a[j][1] = bf2f(v0[j].y);
    a[j][2] = bf2f(v0[j].z); a[j][3] = bf2f(v0[j].w);
  }

#pragma unroll
  for (int j = 0; j < 8; j++) {
    for (int p = lo[j] + 1; p < hi[j]; ++p) {
      int r = rows[p];
      ushort4 v = *(const ushort4*)(h + (size_t)r * D + lane * 4);
      a[j][0] += bf2f(v.x); a[j][1] += bf2f(v.y);
      a[j][2] += bf2f(v.z); a[j][3] += bf2f(v.w);
    }
  }

#pragma unroll
  for (int j = 0; j < 8; j++) {
    int id = base + j;
    if (id >= RN) continue;
    int c = hi[j] - lo[j];
    if (c < 2) continue;                    // not materialized
    float inv = 1.0f / (float)c;
    ushort4 o;
    o.x = f2bf(a[j][0] * inv); o.y = f2bf(a[j][1] * inv);
    o.z = f2bf(a[j][2] * inv); o.w = f2bf(a[j][3] * inv);
    *(ushort4*)(out + (size_t)id * D + lane * 4) = o;
  }
}

// ---------------- zero the graph-sum accumulator (capture-safe, r9-proven) -
__global__ __launch_bounds__(256) void k_zerog(float* __restrict__ gsum, int n4) {
  int i = blockIdx.x * 256 + threadIdx.x;
  if (i < n4) ((float4*)gsum)[i] = make_float4(0.f, 0.f, 0.f, 0.f);
}

// ---------------- T = tableb @ {root1, W1_r} — 10K-row GEMM (r12-proven) --
__global__ __launch_bounds__(512) void k_tgemm(
    const unsigned short* __restrict__ tableb,
    const unsigned short* __restrict__ wb1,
    unsigned short* __restrict__ T, int VOCN, int nbm) {
  __shared__ unsigned short AsU[2][128 * 32];
  __shared__ unsigned short BsU[2][256 * 32];
  const int tid = threadIdx.x;
  const int w = tid >> 6, lane = tid & 63;
  const int wr = w >> 2, wc = w & 3;
  const int mat = blockIdx.x / nbm;
  const int i0 = (blockIdx.x % nbm) * 128;
  const int ml = lane & 15, q = lane >> 4;

  const int arow = w * 16 + (lane >> 2);
  const int achunk = lane & 3;
  int ra = i0 + arow;
  int rac = (ra < VOCN) ? ra : (VOCN - 1);
  const unsigned short* abase = tableb + (size_t)rac * D + achunk * 8;

  const int brow = w * 32 + (lane >> 2);
  const int bchunk = lane & 3;
  const unsigned short* bbase = wb1 + (size_t)mat * 65536
                              + (size_t)brow * D + bchunk * 8;

  floatx4 acc[4][4];
#pragma unroll
  for (int i = 0; i < 4; i++)
#pragma unroll
    for (int j = 0; j < 4; j++) acc[i][j] = (floatx4){0.f, 0.f, 0.f, 0.f};

  unsigned short* aldst[2] = {&AsU[0][w * 512], &AsU[1][w * 512]};
  unsigned short* bldst0[2] = {&BsU[0][w * 1024], &BsU[1][w * 1024]};
  unsigned short* bldst1[2] = {&BsU[0][w * 1024 + 512], &BsU[1][w * 1024 + 512]};

  for (int step = 0; step < 4; ++step) {
    __syncthreads();
#pragma unroll
    for (int h = 0; h < 2; h++) {
      const int kloc = step * 64 + h * 32;
      glds16(abase + kloc, aldst[h]);
      glds16(bbase + kloc, bldst0[h]);
      glds16(bbase + 16 * D + kloc, bldst1[h]);
    }
    __syncthreads();

#pragma unroll
    for (int h = 0; h < 2; h++) {
      short8 aF[4], bF[4];
#pragma unroll
      for (int mi = 0; mi < 4; mi++)
        aF[mi] = *(const short8*)&AsU[h][(wr * 64 + mi * 16 + ml) * 32 + q * 8];
#pragma unroll
      for (int ni = 0; ni < 4; ni++)
        bF[ni] = *(const short8*)&BsU[h][(wc * 64 + ni * 16 + ml) * 32 + q * 8];
#pragma unroll
      for (int mi = 0; mi < 4; mi++)
#pragma unroll
        for (int ni = 0; ni < 4; ni++)
          acc[mi][ni] = __builtin_amdgcn_mfma_f32_16x16x32_bf16(
              aF[mi], bF[ni], acc[mi][ni], 0, 0, 0);
    }
  }

#pragma unroll
  for (int mi = 0; mi < 4; mi++) {
#pragma unroll
    for (int ni = 0; ni < 4; ni++) {
      int col = wc * 64 + ni * 16 + ml;
#pragma unroll
      for (int j = 0; j < 4; j++) {
        int row = i0 + wr * 64 + mi * 16 + q * 4 + j;
        if (row < VOCN)
          T[((size_t)mat * VOCN + row) * D + col] = f2bf(acc[mi][ni][j]);
      }
    }
  }
}

// ---------------- L1 combine: TWO nodes per wave (r14-proven) -------------
__global__ __launch_bounds__(256) void k_combine(
    const int* __restrict__ x, const int* __restrict__ esx,
    const int* __restrict__ off, const unsigned short* __restrict__ T,
    const float* __restrict__ bias, unsigned short* __restrict__ outP,
    int N, int VOCN) {
  const int wave = threadIdx.x >> 6, lane = threadIdx.x & 63;
  const int base = (blockIdx.x * 4 + wave) * 2;
  if (base >= N) return;
  float4 bv = *(const float4*)(bias + lane * 4);

  int id[2];
  id[0] = base;
  id[1] = (base + 1 < N) ? (base + 1) : base;

  ushort4 rv[2];
  int lo[2][3], hi[2][3];
#pragma unroll
  for (int u = 0; u < 2; u++) {
    rv[u] = *(const ushort4*)(T + (size_t)x[id[u]] * D + lane * 4);
#pragma unroll
    for (int r = 0; r < 3; r++) {
      lo[u][r] = off[r * N + id[u]];
      hi[u][r] = off[r * N + id[u] + 1];
    }
  }
  ushort4 f[2][3];
#pragma unroll
  for (int u = 0; u < 2; u++)
#pragma unroll
    for (int r = 0; r < 3; r++)
      f[u][r] = (hi[u][r] > lo[u][r])
          ? *(const ushort4*)(T + ((size_t)(r + 1) * VOCN + esx[lo[u][r]]) * D
                              + lane * 4)
          : make_ushort4(0, 0, 0, 0);

#pragma unroll
  for (int u = 0; u < 2; u++) {
    float a0 = bf2f(rv[u].x) + bv.x, a1 = bf2f(rv[u].y) + bv.y;
    float a2 = bf2f(rv[u].z) + bv.z, a3 = bf2f(rv[u].w) + bv.w;
#pragma unroll
    for (int r = 0; r < 3; r++) {
      int c = hi[u][r] - lo[u][r];
      if (c <= 0) continue;
      float s0 = bf2f(f[u][r].x), s1 = bf2f(f[u][r].y);
      float s2 = bf2f(f[u][r].z), s3 = bf2f(f[u][r].w);
      for (int p = lo[u][r] + 1; p < hi[u][r]; ++p) {
        ushort4 w = *(const ushort4*)(T + ((size_t)(r + 1) * VOCN + esx[p]) * D
                                      + lane * 4);
        s0 += bf2f(w.x); s1 += bf2f(w.y); s2 += bf2f(w.z); s3 += bf2f(w.w);
      }
      float inv = 1.0f / (float)c;
      a0 += s0 * inv; a1 += s1 * inv; a2 += s2 * inv; a3 += s3 * inv;
    }
    ushort4 o;
    o.x = f2bf(fmaxf(a0, 0.f)); o.y = f2bf(fmaxf(a1, 0.f));
    o.z = f2bf(fmaxf(a2, 0.f)); o.w = f2bf(fmaxf(a3, 0.f));
    *(ushort4*)(outP + (size_t)id[u] * D + lane * 4) = o;
  }
}

// ---------------- fused K=1024 bf16 MFMA GEMM + collision-free pool -------
// r17: r16 GEMM core (78us). When gsum!=null (L2): epilogue pools into
// gsum INSTEAD of writing C. Fourth attempt, prior failure mechanisms
// fixed: r9 (25.6M contended global atomics) and r11 (25.6M LDS float
// atomics w/ 4-way intra-wave same-address collisions, likely CAS loops)
// -> now PLAIN LDS stores: each thread pre-reduces its 64 values per
// (gl,ni) and stores to lred[(wr*4+q)][gl][col] (dead 32KB BsU) — the
// (wr,q,wc,ml,ni) -> word mapping has exactly one owner, ZERO collisions,
// zero atomics. Final: nspan*256 global atomics/block (~400K total, ~3/
// word — k_count_i scale). Fast path nspan<=4 (avg graph=195 rows, nearly
// all blocks); rare nspan>4 -> direct per-value global atomics. Pool math
// fp32-pre-bf16 r9-proven (passed, absmax unchanged).
__global__ __launch_bounds__(512) void k_lgemm(
    const unsigned short* __restrict__ Aroot, const int* __restrict__ gidx,
    const unsigned short* agg, const int* __restrict__ rows_,
    const int* __restrict__ off_, const unsigned short* __restrict__ zrow,
    const unsigned short* __restrict__ wb,
    const float* __restrict__ bias, unsigned short* __restrict__ Cout,
    const int* __restrict__ batchv, float* __restrict__ gsum, int M, int N) {
  __shared__ unsigned short AsU[2][128 * 32];    // 2 x 8 KB  [row][k]
  __shared__ unsigned short BsU[2][256 * 32];    // 2 x 16 KB [n][k]
  const int tid = threadIdx.x;
  const int w = tid >> 6, lane = tid & 63;
  const int wr = w >> 2, wc = w & 3;             // wave grid 2x4
  const int i0 = blockIdx.x * 128;
  const int ml = lane & 15, q = lane >> 4;

  // A staging: wave w stages rows w*16..w*16+15 (1 KB / instr).
  const int arow = w * 16 + (lane >> 2);
  const int achunk = lane & 3;
  int ra = i0 + arow;
  int rac = (ra < M) ? ra : (M - 1);
  const int rowA0 = gidx ? gidx[rac] : rac;
  const unsigned short* abase[4];
  abase[0] = Aroot + (size_t)rowA0 * D + achunk * 8;
#pragma unroll
  for (int r = 0; r < 3; r++) {
    int id = r * N + rac;
    int lo = off_[id];
    int cnt = off_[id + 1] - lo;
    const unsigned short* b;
    if (cnt == 0) b = zrow;                        // exact zeros
    else if (cnt == 1) b = Aroot + (size_t)rows_[lo] * D;  // mean of 1
    else b = agg + (size_t)id * D;                 // materialized
    abase[r + 1] = b + achunk * 8;
  }

  // B staging: wave w stages rows w*32..w*32+31 (2 instrs of 1 KB).
  const int brow = w * 32 + (lane >> 2);
  const int bchunk = lane & 3;
  const size_t bofs = (size_t)brow * D + bchunk * 8;

  floatx4 acc[4][4];
#pragma unroll
  for (int i = 0; i < 4; i++)
#pragma unroll
    for (int j = 0; j < 4; j++) acc[i][j] = (floatx4){0.f, 0.f, 0.f, 0.f};

  unsigned short* aldst[2] = {&AsU[0][w * 512], &AsU[1][w * 512]};
  unsigned short* bldst0[2] = {&BsU[0][w * 1024], &BsU[1][w * 1024]};
  unsigned short* bldst1[2] = {&BsU[0][w * 1024 + 512], &BsU[1][w * 1024 + 512]};

  for (int step = 0; step < 16; ++step) {
    __syncthreads();                    // previous step's LDS reads done
#pragma unroll
    for (int h = 0; h < 2; h++) {
      const int kabs = step * 64 + h * 32;
      const int seg = kabs >> 8, kloc = kabs & 255;
      glds16(abase[seg] + kloc, aldst[h]);
      const unsigned short* bb = wb + (size_t)seg * 65536 + bofs + kloc;
      glds16(bb, bldst0[h]);
      glds16(bb + 16 * D, bldst1[h]);
    }
    __syncthreads();                    // vmcnt drained -> LDS populated

#pragma unroll
    for (int h = 0; h < 2; h++) {
      short8 aF[4], bF[4];
#pragma unroll
      for (int mi = 0; mi < 4; mi++)
        aF[mi] = *(const short8*)&AsU[h][(wr * 64 + mi * 16 + ml) * 32 + q * 8];
#pragma unroll
      for (int ni = 0; ni < 4; ni++)
        bF[ni] = *(const short8*)&BsU[h][(wc * 64 + ni * 16 + ml) * 32 + q * 8];
#pragma unroll
      for (int mi = 0; mi < 4; mi++)
#pragma unroll
        for (int ni = 0; ni < 4; ni++)
          acc[mi][ni] = __builtin_amdgcn_mfma_f32_16x16x32_bf16(
              aF[mi], bF[ni], acc[mi][ni], 0, 0, 0);
    }
  }

  // K-loop LDS reads done; reads of input pages precede any writes below
  __syncthreads();

  // epilogue: bias + ReLU; C/D layout col=lane&15, row=q*4+reg
  float bv[4];
#pragma unroll
  for (int ni = 0; ni < 4; ni++) bv[ni] = bias[wc * 64 + ni * 16 + ml];

  if (gsum) {
    // ---- collision-free block pool (layer 2) ----
    int lastrow = (i0 + 127 < M) ? (i0 + 127) : (M - 1);
    int gfirst = batchv[(i0 < M) ? i0 : (M - 1)];
    int glast = batchv[lastrow];
    int nspan = glast - gfirst + 1;
    // per-thread graph ids for its 16 rows
    int gb[4][4];
#pragma unroll
    for (int mi = 0; mi < 4; mi++)
#pragma unroll
      for (int j = 0; j < 4; j++) {
        int row = i0 + wr * 64 + mi * 16 + q * 4 + j;
        gb[mi][j] = (row < M) ? batchv[row] : -1;
      }
    if (nspan <= 4) {
      float* lred = (float*)&BsU[0][0];   // 32 KB dead LDS: [8][4][256]
      const int slot = wr * 4 + q;
      for (int gl = 0; gl < nspan; gl++) {
        int g = gfirst + gl;
#pragma unroll
        for (int ni = 0; ni < 4; ni++) {
          float s = 0.f;
#pragma unroll
          for (int mi = 0; mi < 4; mi++)
#pragma unroll
            for (int j = 0; j < 4; j++)
              if (gb[mi][j] == g)
                s += fmaxf(acc[mi][ni][j] + bv[ni], 0.f);
          int col = wc * 64 + ni * 16 + ml;
          lred[(slot * 4 + gl) * 256 + col] = s;   // unique owner: no races
        }
      }
      __syncthreads();
      for (int idx = tid; idx < nspan * 256; idx += 512) {
        int gl = idx >> 8, col = idx & 255;
        float s = 0.f;
#pragma unroll
        for (int sl = 0; sl < 8; sl++)
          s += lred[(sl * 4 + gl) * 256 + col];
        atomicAdd(&gsum[(size_t)(gfirst + gl) * D + col], s);
      }
    } else {
      // rare: >4 graphs in 128 rows — direct per-value atomics
#pragma unroll
      for (int mi = 0; mi < 4; mi++)
#pragma unroll
        for (int j = 0; j < 4; j++) {
          if (gb[mi][j] < 0) continue;
#pragma unroll
          for (int ni = 0; ni < 4; ni++) {
            int col = wc * 64 + ni * 16 + ml;
            atomicAdd(&gsum[(size_t)gb[mi][j] * D + col],
                      fmaxf(acc[mi][ni][j] + bv[ni], 0.f));
          }
        }
    }
  } else {
#pragma unroll
    for (int mi = 0; mi < 4; mi++) {
#pragma unroll
      for (int ni = 0; ni < 4; ni++) {
        int col = wc * 64 + ni * 16 + ml;
#pragma unroll
        for (int j = 0; j < 4; j++) {
          int row = i0 + wr * 64 + mi * 16 + q * 4 + j;
          if (row < M) {
            float v = fmaxf(acc[mi][ni][j] + bv[ni], 0.f);
            Cout[(size_t)row * D + col] = f2bf(v);
          }
        }
      }
    }
  }
}

// ---------------- final: graph mean + linear head from gsum (r9-proven) ---
__global__ __launch_bounds__(64) void k_final(
    const float* __restrict__ gsum, const int* __restrict__ gstart,
    const float* __restrict__ linW, const float* __restrict__ linb,
    float* __restrict__ out, int G) {
  int g = blockIdx.x, lane = threadIdx.x;      // 64 lanes, 4 features each
  int cnt = gstart[g + 1] - gstart[g];
  float inv = (cnt > 0) ? 1.0f / (float)cnt : 0.0f;
  float4 s = *(const float4*)(gsum + (size_t)g * D + lane * 4);
  float m0 = s.x * inv, m1 = s.y * inv, m2 = s.z * inv, m3 = s.w * inv;
  float4 w0 = *(const float4*)(linW + (lane * 4 + 0) * 4);
  float4 w1 = *(const float4*)(linW + (lane * 4 + 1) * 4);
  float4 w2 = *(const float4*)(linW + (lane * 4 + 2) * 4);
  float4 w3 = *(const float4*)(linW + (lane * 4 + 3) * 4);
  float p0 = m0 * w0.x + m1 * w1.x + m2 * w2.x + m3 * w3.x;
  float p1 = m0 * w0.y + m1 * w1.y + m2 * w2.y + m3 * w3.y;
  float p2 = m0 * w0.z + m1 * w1.z + m2 * w2.z + m3 * w3.z;
  float p3 = m0 * w0.w + m1 * w1.w + m2 * w2.w + m3 * w3.w;
  for (int o = 32; o > 0; o >>= 1) {
    p0 += __shfl_down(p0, o, 64);
    p1 += __shfl_down(p1, o, 64);
    p2 += __shfl_down(p2, o, 64);
    p3 += __shfl_down(p3, o, 64);
  }
  if (lane == 0) {
    out[g * 4 + 0] = p0 + linb[0];
    out[g * 4 + 1] = p1 + linb[1];
    out[g * 4 + 2] = p2 + linb[2];
    out[g * 4 + 3] = p3 + linb[3];
  }
}

extern "C" void kernel_launch(void* const* d_in, const int* in_sizes, int n_in,
                              void* d_out, int out_size, void* d_ws, size_t ws_size,
                              hipStream_t stream) {
  const int*   x     = (const int*)d_in[0];
  const int*   ei    = (const int*)d_in[1];
  const int*   et    = (const int*)d_in[2];
  const int*   batch = (const int*)d_in[3];
  const float* table = (const float*)d_in[5];
  const float* W1    = (const float*)d_in[6];
  const float* root1 = (const float*)d_in[7];
  const float* b1    = (const float*)d_in[8];
  const float* W2    = (const float*)d_in[9];
  const float* root2 = (const float*)d_in[10];
  const float* b2    = (const float*)d_in[11];
  const float* linW  = (const float*)d_in[12];
  const float* linb  = (const float*)d_in[13];
  float* out = (float*)d_out;

  const int N = in_sizes[0];
  const int E = in_sizes[2];
  const int G = out_size / 4;
  const int VOC = in_sizes[5] / D;
  const int* src = ei;
  const int* dst = ei + E;
  const int RN = 3 * N;

  // ---- ws layout, page aliasing proven rounds 5-17 ----
  char* wsb = (char*)d_ws;
  size_t pg = (size_t)N * D * 2;
  unsigned short* P0 = (unsigned short*)wsb;
  unsigned short* P1 = (unsigned short*)(wsb + pg);
  unsigned short* P3 = (unsigned short*)(wsb + 3 * pg);
  unsigned short* wb = (unsigned short*)(wsb + 4 * pg);  // 2 layers x 4 mats
  unsigned short* zrow = wb + 2 * 4 * 65536;   // 256 shorts (512 B zero row)
  int*   off    = (int*)(zrow + 256);
  int*   esx    = off + (RN + 1);       // L1 row ids (= x[src])
  int*   ess    = esx + E;              // L2 row ids (= src)
  int*   gstart = ess + E;
  unsigned short* tableb = P3;          // alias (dead after k_tgemm)
  unsigned short* Tbuf = P1;            // 4 x VOC x 256 bf16 = 20 MB in page1;
                                        // dead before L2 agg writes pages 1-3
  int* cur  = (int*)P0;                 // alias (dead before combine writes P0)
  int* bsum = cur + RN;                 // alias
  // gsum aliases esx (dead after k_combine); 16B-align for float4
  float* gsum = (float*)((((size_t)esx) + 15) & ~(size_t)15);

  const int nb = (RN + SB - 1) / SB;

  // ---- setup: one fused kernel for all independent prep ----
  int nbZero = (RN + 1023) / 1024;
  int nbBounds = (N + 255) / 256;
  int nbCvt = (VOC * D / 8 + 255) / 256;     // x8 vectorized table cvt
  int g0 = nbZero, g1 = g0 + nbBounds, g2 = g1 + nbCvt, g3 = g2 + 256;
  k_setup<<<g3 + 256, 256, 0, stream>>>(cur, RN, batch, gstart, N, G,
      table, tableb, VOC * D, root1, W1, root2, W2, wb, (int*)zrow,
      g0, g1, g2, g3);

  // T depends only on setup — run before the CSR chain
  const int nbm = (VOC + 127) / 128;
  k_tgemm<<<nbm * 4, 512, 0, stream>>>(tableb, wb, Tbuf, VOC, nbm);

  k_count_i<<<(E + 255) / 256, 256, 0, stream>>>(dst, et, cur, E, N);
  k_scan1<<<nb, 256, 0, stream>>>(cur, bsum, RN);
  k_scan2<<<1, 256, 0, stream>>>(bsum, nb, off + RN);
  k_scan3<<<nb, 256, 0, stream>>>(cur, bsum, off, cur, RN);
  k_place2<<<(E + 255) / 256, 256, 0, stream>>>(src, dst, et, x, cur, esx, ess, E, N);

  // ---- layer 1 (algebraic): combine gathers from T ----
  k_combine<<<(N + 7) / 8, 256, 0, stream>>>(x, esx, off, Tbuf, b1, P0, N, VOC);

  // esx dead from here; zero the graph-sum buffer that aliases it
  k_zerog<<<(G * D / 4 + 255) / 256, 256, 0, stream>>>(gsum, G * D / 4);

  const int gagg = (RN + 31) / 32;      // 8 ids/wave x 4 waves
  const int ggemm = (N + 127) / 128;

  // ---- layer 2: agg + GEMM with fused collision-free pool ----
  k_agg<<<gagg, 256, 0, stream>>>(P0, ess, off, P1, RN);
  k_lgemm<<<ggemm, 512, 0, stream>>>(P0, nullptr, P1, ess, off, zrow,
                                     wb + 4 * 65536, b2, nullptr, batch, gsum,
                                     N, N);

  // ---- mean + linear head ----
  k_final<<<G, 64, 0, stream>>>(gsum, gstart, linW, linb, out, G);
}

// Round 18
// 305.403 us; speedup vs baseline: 1.1394x; 1.1394x over previous
//
#include <hip/hip_runtime.h>

#define D 256
#define SB 1024
typedef __attribute__((ext_vector_type(8))) short short8;
typedef __attribute__((ext_vector_type(4))) float floatx4;

__device__ __forceinline__ unsigned short f2bf(float f) {
  unsigned int u = __float_as_uint(f);
  u = (u + 0x7FFF + ((u >> 16) & 1)) >> 16;   // RNE
  return (unsigned short)u;
}
__device__ __forceinline__ float bf2f(unsigned short h) {
  return __uint_as_float(((unsigned int)h) << 16);
}

// async global->LDS, 16B per lane; LDS dest = wave-uniform base + lane*16
__device__ __forceinline__ void glds16(const void* g, void* l) {
  __builtin_amdgcn_global_load_lds(
      (const __attribute__((address_space(1))) unsigned int*)g,
      (__attribute__((address_space(3))) unsigned int*)l, 16, 0, 0);
}

// ---------------- fused independent setup: zero | bounds | cvt | cvt_w x2 --
// r27: table cvt x8 (G13). r14: weight cvt x4 (ushort4 stores).
__global__ __launch_bounds__(256) void k_setup(
    int* __restrict__ cur, int RN,
    const int* __restrict__ batch, int* __restrict__ gstart, int N, int G,
    const float* __restrict__ table, unsigned short* __restrict__ tableb, int TN,
    const float* __restrict__ root1, const float* __restrict__ W1,
    const float* __restrict__ root2, const float* __restrict__ W2,
    unsigned short* __restrict__ wb, int* __restrict__ zrowi,
    int g0, int g1, int g2, int g3) {
  int b = blockIdx.x, t = threadIdx.x;
  if (b < g0) {                       // zero cur, int4 per thread
    int i = b * 1024 + t * 4;
#pragma unroll
    for (int j = 0; j < 4; j++) if (i + j < RN) cur[i + j] = 0;
    if (b == 0 && t < 128) zrowi[t] = 0;   // 512B zero feature row
  } else if (b < g1) {                // graph bounds
    int i = (b - g0) * 256 + t;
    if (i >= N) return;
    int bb = batch[i];
    if (i == 0) { for (int g = 0; g <= bb; g++) gstart[g] = 0; }
    else { int pb = batch[i - 1]; for (int g = pb + 1; g <= bb; g++) gstart[g] = i; }
    if (i == N - 1) { for (int g = bb + 1; g <= G; g++) gstart[g] = N; }
  } else if (b < g2) {                // table fp32 -> bf16, 8 elems/thread
    int i = ((b - g1) * 256 + t) * 8;
    if (i < TN) {
      float4 f0 = *(const float4*)(table + i);
      float4 f1 = *(const float4*)(table + i + 4);
      ushort4 o0, o1;
      o0.x = f2bf(f0.x); o0.y = f2bf(f0.y); o0.z = f2bf(f0.z); o0.w = f2bf(f0.w);
      o1.x = f2bf(f1.x); o1.y = f2bf(f1.y); o1.z = f2bf(f1.z); o1.w = f2bf(f1.w);
      *(ushort4*)(tableb + i) = o0;
      *(ushort4*)(tableb + i + 4) = o1;
    }
  } else {                            // weights -> bf16 transposed, 4/thread
    int layer = (b < g3) ? 0 : 1;
    int idx4 = ((b - (layer ? g3 : g2)) * 256 + t) * 4;  // 0..262140, step 4
    int mat = idx4 >> 16, rem = idx4 & 65535;
    int n = rem >> 8, k0 = rem & 255;
    const float* root = layer ? root2 : root1;
    const float* W = layer ? W2 : W1;
    const float* s = (mat == 0) ? root : (W + (size_t)(mat - 1) * 65536);
    ushort4 o;
    o.x = f2bf(s[(k0 + 0) * 256 + n]);
    o.y = f2bf(s[(k0 + 1) * 256 + n]);
    o.z = f2bf(s[(k0 + 2) * 256 + n]);
    o.w = f2bf(s[(k0 + 3) * 256 + n]);
    *(ushort4*)(wb + (size_t)layer * 4 * 65536 + idx4) = o;
  }
}

// ---------------- per-(relation,node) in-edge counts ----------------
__global__ __launch_bounds__(256) void k_count_i(const int* __restrict__ dst,
    const int* __restrict__ et, int* __restrict__ cnt, int E, int N) {
  int e = blockIdx.x * 256 + threadIdx.x;
  if (e >= E) return;
  atomicAdd(&cnt[et[e] * N + dst[e]], 1);
}

// ---------------- 3-kernel scan chain (proven r11/r14) ----------------
__global__ __launch_bounds__(256) void k_scan1(const int* __restrict__ in,
    int* __restrict__ bsum, int n) {
  __shared__ int s[256];
  int base = blockIdx.x * SB, t = threadIdx.x;
  int a = 0;
#pragma unroll
  for (int j = 0; j < 4; j++) { int i = base + t * 4 + j; if (i < n) a += in[i]; }
  s[t] = a; __syncthreads();
  for (int o = 128; o > 0; o >>= 1) { if (t < o) s[t] += s[t + o]; __syncthreads(); }
  if (t == 0) bsum[blockIdx.x] = s[0];
}

__global__ __launch_bounds__(256) void k_scan2(int* __restrict__ bsum, int nb,
    int* __restrict__ total_out) {
  __shared__ int s[256];
  int t = threadIdx.x;
  int v[4]; int a = 0;
#pragma unroll
  for (int j = 0; j < 4; j++) {
    int i = t * 4 + j;
    v[j] = (i < nb) ? bsum[i] : 0;
    a += v[j];
  }
  s[t] = a; __syncthreads();
  for (int o = 1; o < 256; o <<= 1) {
    int x_ = (t >= o) ? s[t - o] : 0;
    __syncthreads();
    s[t] += x_;
    __syncthreads();
  }
  int excl = (t > 0) ? s[t - 1] : 0;
#pragma unroll
  for (int j = 0; j < 4; j++) {
    int i = t * 4 + j;
    if (i < nb) { bsum[i] = excl; excl += v[j]; }
  }
  if (t == 255) *total_out = s[255];
}

__global__ __launch_bounds__(256) void k_scan3(const int* __restrict__ in,
    const int* __restrict__ bsum, int* __restrict__ off, int* __restrict__ cur,
    int n) {
  __shared__ int s[256];
  int base = blockIdx.x * SB, t = threadIdx.x;
  int v[4]; int a = 0;
#pragma unroll
  for (int j = 0; j < 4; j++) {
    int i = base + t * 4 + j;
    v[j] = (i < n) ? in[i] : 0;
    a += v[j];
  }
  s[t] = a; __syncthreads();
  for (int o = 1; o < 256; o <<= 1) {
    int x_ = (t >= o) ? s[t - o] : 0;
    __syncthreads();
    s[t] += x_;
    __syncthreads();
  }
  int excl = (t > 0 ? s[t - 1] : 0) + bsum[blockIdx.x];
#pragma unroll
  for (int j = 0; j < 4; j++) {
    int i = base + t * 4 + j;
    if (i < n) { off[i] = excl; cur[i] = excl; excl += v[j]; }
  }
}

// CSR placement: esx[pos] = x[src] (L1 row id), ess[pos] = src (L2 row id)
__global__ __launch_bounds__(256) void k_place2(const int* __restrict__ src,
    const int* __restrict__ dst, const int* __restrict__ et,
    const int* __restrict__ x, int* __restrict__ cur,
    int* __restrict__ esx, int* __restrict__ ess, int E, int N) {
  int e = blockIdx.x * 256 + threadIdx.x;
  if (e >= E) return;
  int s = src[e];
  int pos = atomicAdd(&cur[et[e] * N + dst[e]], 1);
  esx[pos] = x[s];
  ess[pos] = s;
}

// ---------------- relation aggregation, 8 ids per wave, MULTI-EDGE ONLY ---
// (L2 only) r6-proven: cnt==0/1 ids not materialized.
__global__ __launch_bounds__(256) void k_agg(const unsigned short* __restrict__ h,
    const int* __restrict__ rows, const int* __restrict__ off,
    unsigned short* __restrict__ out, int RN) {
  const int wave = threadIdx.x >> 6, lane = threadIdx.x & 63;
  const int base = (blockIdx.x * 4 + wave) * 8;
  if (base >= RN) return;

  int lo[8], hi[8];
#pragma unroll
  for (int j = 0; j < 8; j++) {
    int id = base + j;
    lo[j] = (id < RN) ? off[id] : 0;
    hi[j] = (id < RN) ? off[id + 1] : 0;
    if (hi[j] - lo[j] < 2) hi[j] = lo[j];   // skip: handled by GEMM gather
  }

  int r0[8];
#pragma unroll
  for (int j = 0; j < 8; j++)
    r0[j] = (hi[j] > lo[j]) ? rows[lo[j]] : 0;

  ushort4 v0[8];
#pragma unroll
  for (int j = 0; j < 8; j++)
    v0[j] = (hi[j] > lo[j])
        ? *(const ushort4*)(h + (size_t)r0[j] * D + lane * 4)
        : make_ushort4(0, 0, 0, 0);

  float a[8][4];
#pragma unroll
  for (int j = 0; j < 8; j++) {
    a[j][0] = bf2f(v0[j].x); a[j][1] = bf2f(v0[j].y);
    a[j][2] = bf2f(v0[j].z); a[j][3] = bf2f(v0[j].w);
  }

#pragma unroll
  for (int j = 0; j < 8; j++) {
    for (int p = lo[j] + 1; p < hi[j]; ++p) {
      int r = rows[p];
      ushort4 v = *(const ushort4*)(h + (size_t)r * D + lane * 4);
      a[j][0] += bf2f(v.x); a[j][1] += bf2f(v.y);
      a[j][2] += bf2f(v.z); a[j][3] += bf2f(v.w);
    }
  }

#pragma unroll
  for (int j = 0; j < 8; j++) {
    int id = base + j;
    if (id >= RN) continue;
    int c = hi[j] - lo[j];
    if (c < 2) continue;                    // not materialized
    float inv = 1.0f / (float)c;
    ushort4 o;
    o.x = f2bf(a[j][0] * inv); o.y = f2bf(a[j][1] * inv);
    o.z = f2bf(a[j][2] * inv); o.w = f2bf(a[j][3] * inv);
    *(ushort4*)(out + (size_t)id * D + lane * 4) = o;
  }
}

// ---------------- zero the graph-sum accumulator (capture-safe, r9-proven) -
__global__ __launch_bounds__(256) void k_zerog(float* __restrict__ gsum, int n4) {
  int i = blockIdx.x * 256 + threadIdx.x;
  if (i < n4) ((float4*)gsum)[i] = make_float4(0.f, 0.f, 0.f, 0.f);
}

// ---------------- T = tableb @ {root1, W1_r} — 10K-row GEMM (r12-proven) --
__global__ __launch_bounds__(512) void k_tgemm(
    const unsigned short* __restrict__ tableb,
    const unsigned short* __restrict__ wb1,
    unsigned short* __restrict__ T, int VOCN, int nbm) {
  __shared__ unsigned short AsU[2][128 * 32];
  __shared__ unsigned short BsU[2][256 * 32];
  const int tid = threadIdx.x;
  const int w = tid >> 6, lane = tid & 63;
  const int wr = w >> 2, wc = w & 3;
  const int mat = blockIdx.x / nbm;
  const int i0 = (blockIdx.x % nbm) * 128;
  const int ml = lane & 15, q = lane >> 4;

  const int arow = w * 16 + (lane >> 2);
  const int achunk = lane & 3;
  int ra = i0 + arow;
  int rac = (ra < VOCN) ? ra : (VOCN - 1);
  const unsigned short* abase = tableb + (size_t)rac * D + achunk * 8;

  const int brow = w * 32 + (lane >> 2);
  const int bchunk = lane & 3;
  const unsigned short* bbase = wb1 + (size_t)mat * 65536
                              + (size_t)brow * D + bchunk * 8;

  floatx4 acc[4][4];
#pragma unroll
  for (int i = 0; i < 4; i++)
#pragma unroll
    for (int j = 0; j < 4; j++) acc[i][j] = (floatx4){0.f, 0.f, 0.f, 0.f};

  unsigned short* aldst[2] = {&AsU[0][w * 512], &AsU[1][w * 512]};
  unsigned short* bldst0[2] = {&BsU[0][w * 1024], &BsU[1][w * 1024]};
  unsigned short* bldst1[2] = {&BsU[0][w * 1024 + 512], &BsU[1][w * 1024 + 512]};

  for (int step = 0; step < 4; ++step) {
    __syncthreads();
#pragma unroll
    for (int h = 0; h < 2; h++) {
      const int kloc = step * 64 + h * 32;
      glds16(abase + kloc, aldst[h]);
      glds16(bbase + kloc, bldst0[h]);
      glds16(bbase + 16 * D + kloc, bldst1[h]);
    }
    __syncthreads();

#pragma unroll
    for (int h = 0; h < 2; h++) {
      short8 aF[4], bF[4];
#pragma unroll
      for (int mi = 0; mi < 4; mi++)
        aF[mi] = *(const short8*)&AsU[h][(wr * 64 + mi * 16 + ml) * 32 + q * 8];
#pragma unroll
      for (int ni = 0; ni < 4; ni++)
        bF[ni] = *(const short8*)&BsU[h][(wc * 64 + ni * 16 + ml) * 32 + q * 8];
#pragma unroll
      for (int mi = 0; mi < 4; mi++)
#pragma unroll
        for (int ni = 0; ni < 4; ni++)
          acc[mi][ni] = __builtin_amdgcn_mfma_f32_16x16x32_bf16(
              aF[mi], bF[ni], acc[mi][ni], 0, 0, 0);
    }
  }

#pragma unroll
  for (int mi = 0; mi < 4; mi++) {
#pragma unroll
    for (int ni = 0; ni < 4; ni++) {
      int col = wc * 64 + ni * 16 + ml;
#pragma unroll
      for (int j = 0; j < 4; j++) {
        int row = i0 + wr * 64 + mi * 16 + q * 4 + j;
        if (row < VOCN)
          T[((size_t)mat * VOCN + row) * D + col] = f2bf(acc[mi][ni][j]);
      }
    }
  }
}

// ---------------- L1 combine: TWO nodes per wave (r14-proven) -------------
__global__ __launch_bounds__(256) void k_combine(
    const int* __restrict__ x, const int* __restrict__ esx,
    const int* __restrict__ off, const unsigned short* __restrict__ T,
    const float* __restrict__ bias, unsigned short* __restrict__ outP,
    int N, int VOCN) {
  const int wave = threadIdx.x >> 6, lane = threadIdx.x & 63;
  const int base = (blockIdx.x * 4 + wave) * 2;
  if (base >= N) return;
  float4 bv = *(const float4*)(bias + lane * 4);

  int id[2];
  id[0] = base;
  id[1] = (base + 1 < N) ? (base + 1) : base;

  ushort4 rv[2];
  int lo[2][3], hi[2][3];
#pragma unroll
  for (int u = 0; u < 2; u++) {
    rv[u] = *(const ushort4*)(T + (size_t)x[id[u]] * D + lane * 4);
#pragma unroll
    for (int r = 0; r < 3; r++) {
      lo[u][r] = off[r * N + id[u]];
      hi[u][r] = off[r * N + id[u] + 1];
    }
  }
  ushort4 f[2][3];
#pragma unroll
  for (int u = 0; u < 2; u++)
#pragma unroll
    for (int r = 0; r < 3; r++)
      f[u][r] = (hi[u][r] > lo[u][r])
          ? *(const ushort4*)(T + ((size_t)(r + 1) * VOCN + esx[lo[u][r]]) * D
                              + lane * 4)
          : make_ushort4(0, 0, 0, 0);

#pragma unroll
  for (int u = 0; u < 2; u++) {
    float a0 = bf2f(rv[u].x) + bv.x, a1 = bf2f(rv[u].y) + bv.y;
    float a2 = bf2f(rv[u].z) + bv.z, a3 = bf2f(rv[u].w) + bv.w;
#pragma unroll
    for (int r = 0; r < 3; r++) {
      int c = hi[u][r] - lo[u][r];
      if (c <= 0) continue;
      float s0 = bf2f(f[u][r].x), s1 = bf2f(f[u][r].y);
      float s2 = bf2f(f[u][r].z), s3 = bf2f(f[u][r].w);
      for (int p = lo[u][r] + 1; p < hi[u][r]; ++p) {
        ushort4 w = *(const ushort4*)(T + ((size_t)(r + 1) * VOCN + esx[p]) * D
                                      + lane * 4);
        s0 += bf2f(w.x); s1 += bf2f(w.y); s2 += bf2f(w.z); s3 += bf2f(w.w);
      }
      float inv = 1.0f / (float)c;
      a0 += s0 * inv; a1 += s1 * inv; a2 += s2 * inv; a3 += s3 * inv;
    }
    ushort4 o;
    o.x = f2bf(fmaxf(a0, 0.f)); o.y = f2bf(fmaxf(a1, 0.f));
    o.z = f2bf(fmaxf(a2, 0.f)); o.w = f2bf(fmaxf(a3, 0.f));
    *(ushort4*)(outP + (size_t)id[u] * D + lane * 4) = o;
  }
}

// ---------------- fused K=1024 bf16 MFMA GEMM (r16 core, C-write) ---------
__global__ __launch_bounds__(512) void k_lgemm(
    const unsigned short* __restrict__ Aroot, const int* __restrict__ gidx,
    const unsigned short* agg, const int* __restrict__ rows_,
    const int* __restrict__ off_, const unsigned short* __restrict__ zrow,
    const unsigned short* __restrict__ wb,
    const float* __restrict__ bias, unsigned short* Cout, int M, int N) {
  __shared__ unsigned short AsU[2][128 * 32];    // 2 x 8 KB  [row][k]
  __shared__ unsigned short BsU[2][256 * 32];    // 2 x 16 KB [n][k]
  const int tid = threadIdx.x;
  const int w = tid >> 6, lane = tid & 63;
  const int wr = w >> 2, wc = w & 3;             // wave grid 2x4
  const int i0 = blockIdx.x * 128;
  const int ml = lane & 15, q = lane >> 4;

  const int arow = w * 16 + (lane >> 2);
  const int achunk = lane & 3;
  int ra = i0 + arow;
  int rac = (ra < M) ? ra : (M - 1);
  const int rowA0 = gidx ? gidx[rac] : rac;
  const unsigned short* abase[4];
  abase[0] = Aroot + (size_t)rowA0 * D + achunk * 8;
#pragma unroll
  for (int r = 0; r < 3; r++) {
    int id = r * N + rac;
    int lo = off_[id];
    int cnt = off_[id + 1] - lo;
    const unsigned short* b;
    if (cnt == 0) b = zrow;                        // exact zeros
    else if (cnt == 1) b = Aroot + (size_t)rows_[lo] * D;  // mean of 1
    else b = agg + (size_t)id * D;                 // materialized
    abase[r + 1] = b + achunk * 8;
  }

  const int brow = w * 32 + (lane >> 2);
  const int bchunk = lane & 3;
  const size_t bofs = (size_t)brow * D + bchunk * 8;

  floatx4 acc[4][4];
#pragma unroll
  for (int i = 0; i < 4; i++)
#pragma unroll
    for (int j = 0; j < 4; j++) acc[i][j] = (floatx4){0.f, 0.f, 0.f, 0.f};

  unsigned short* aldst[2] = {&AsU[0][w * 512], &AsU[1][w * 512]};
  unsigned short* bldst0[2] = {&BsU[0][w * 1024], &BsU[1][w * 1024]};
  unsigned short* bldst1[2] = {&BsU[0][w * 1024 + 512], &BsU[1][w * 1024 + 512]};

  for (int step = 0; step < 16; ++step) {
    __syncthreads();
#pragma unroll
    for (int h = 0; h < 2; h++) {
      const int kabs = step * 64 + h * 32;
      const int seg = kabs >> 8, kloc = kabs & 255;
      glds16(abase[seg] + kloc, aldst[h]);
      const unsigned short* bb = wb + (size_t)seg * 65536 + bofs + kloc;
      glds16(bb, bldst0[h]);
      glds16(bb + 16 * D, bldst1[h]);
    }
    __syncthreads();

#pragma unroll
    for (int h = 0; h < 2; h++) {
      short8 aF[4], bF[4];
#pragma unroll
      for (int mi = 0; mi < 4; mi++)
        aF[mi] = *(const short8*)&AsU[h][(wr * 64 + mi * 16 + ml) * 32 + q * 8];
#pragma unroll
      for (int ni = 0; ni < 4; ni++)
        bF[ni] = *(const short8*)&BsU[h][(wc * 64 + ni * 16 + ml) * 32 + q * 8];
#pragma unroll
      for (int mi = 0; mi < 4; mi++)
#pragma unroll
        for (int ni = 0; ni < 4; ni++)
          acc[mi][ni] = __builtin_amdgcn_mfma_f32_16x16x32_bf16(
              aF[mi], bF[ni], acc[mi][ni], 0, 0, 0);
    }
  }

  __syncthreads();

  float bv[4];
#pragma unroll
  for (int ni = 0; ni < 4; ni++) bv[ni] = bias[wc * 64 + ni * 16 + ml];
#pragma unroll
  for (int mi = 0; mi < 4; mi++) {
#pragma unroll
    for (int ni = 0; ni < 4; ni++) {
      int col = wc * 64 + ni * 16 + ml;
#pragma unroll
      for (int j = 0; j < 4; j++) {
        int row = i0 + wr * 64 + mi * 16 + q * 4 + j;
        if (row < M) {
          float v = fmaxf(acc[mi][ni][j] + bv[ni], 0.f);
          Cout[(size_t)row * D + col] = f2bf(v);
        }
      }
    }
  }
}

// ---------------- L2 GEMM + collision-free pool (SEPARATE kernel, r18) ----
// 5th pool-fusion attempt; mechanisms fixed: r8 capture (k_zerog), r9
// global-atomic storm (block reduction), r11 LDS-atomic collisions (plain
// stores, unique owner), r17 VGPR blowup (124 regs from gb[] cache + dual
// epilogue co-allocation) -> DEDICATED kernel (no gsum branch) + batchv
// staged in dead LDS (sbat, zero register cache). Main loop identical to
// k_lgemm. If this one also regresses, pool fusion is closed for good.
__global__ __launch_bounds__(512) void k_lgemmP(
    const unsigned short* __restrict__ Aroot,
    const unsigned short* agg, const int* __restrict__ rows_,
    const int* __restrict__ off_, const unsigned short* __restrict__ zrow,
    const unsigned short* __restrict__ wb,
    const float* __restrict__ bias,
    const int* __restrict__ batchv, float* __restrict__ gsum, int M, int N) {
  __shared__ unsigned short AsU[2][128 * 32];    // 2 x 8 KB
  __shared__ unsigned short BsU[2][256 * 32];    // 2 x 16 KB
  const int tid = threadIdx.x;
  const int w = tid >> 6, lane = tid & 63;
  const int wr = w >> 2, wc = w & 3;
  const int i0 = blockIdx.x * 128;
  const int ml = lane & 15, q = lane >> 4;

  const int arow = w * 16 + (lane >> 2);
  const int achunk = lane & 3;
  int ra = i0 + arow;
  int rac = (ra < M) ? ra : (M - 1);
  const unsigned short* abase[4];
  abase[0] = Aroot + (size_t)rac * D + achunk * 8;
#pragma unroll
  for (int r = 0; r < 3; r++) {
    int id = r * N + rac;
    int lo = off_[id];
    int cnt = off_[id + 1] - lo;
    const unsigned short* b;
    if (cnt == 0) b = zrow;
    else if (cnt == 1) b = Aroot + (size_t)rows_[lo] * D;
    else b = agg + (size_t)id * D;
    abase[r + 1] = b + achunk * 8;
  }

  const int brow = w * 32 + (lane >> 2);
  const int bchunk = lane & 3;
  const size_t bofs = (size_t)brow * D + bchunk * 8;

  floatx4 acc[4][4];
#pragma unroll
  for (int i = 0; i < 4; i++)
#pragma unroll
    for (int j = 0; j < 4; j++) acc[i][j] = (floatx4){0.f, 0.f, 0.f, 0.f};

  unsigned short* aldst[2] = {&AsU[0][w * 512], &AsU[1][w * 512]};
  unsigned short* bldst0[2] = {&BsU[0][w * 1024], &BsU[1][w * 1024]};
  unsigned short* bldst1[2] = {&BsU[0][w * 1024 + 512], &BsU[1][w * 1024 + 512]};

  for (int step = 0; step < 16; ++step) {
    __syncthreads();
#pragma unroll
    for (int h = 0; h < 2; h++) {
      const int kabs = step * 64 + h * 32;
      const int seg = kabs >> 8, kloc = kabs & 255;
      glds16(abase[seg] + kloc, aldst[h]);
      const unsigned short* bb = wb + (size_t)seg * 65536 + bofs + kloc;
      glds16(bb, bldst0[h]);
      glds16(bb + 16 * D, bldst1[h]);
    }
    __syncthreads();

#pragma unroll
    for (int h = 0; h < 2; h++) {
      short8 aF[4], bF[4];
#pragma unroll
      for (int mi = 0; mi < 4; mi++)
        aF[mi] = *(const short8*)&AsU[h][(wr * 64 + mi * 16 + ml) * 32 + q * 8];
#pragma unroll
      for (int ni = 0; ni < 4; ni++)
        bF[ni] = *(const short8*)&BsU[h][(wc * 64 + ni * 16 + ml) * 32 + q * 8];
#pragma unroll
      for (int mi = 0; mi < 4; mi++)
#pragma unroll
        for (int ni = 0; ni < 4; ni++)
          acc[mi][ni] = __builtin_amdgcn_mfma_f32_16x16x32_bf16(
              aF[mi], bF[ni], acc[mi][ni], 0, 0, 0);
    }
  }

  __syncthreads();                    // K-loop LDS dead from here

  // stage this block's batch ids into dead LDS (no register cache)
  int* sbat = (int*)&AsU[0][0];       // 512 B of dead AsU
  if (tid < 128) {
    int row = i0 + tid;
    sbat[tid] = batchv[(row < M) ? row : (M - 1)];
  }
  __syncthreads();

  float bv[4];
#pragma unroll
  for (int ni = 0; ni < 4; ni++) bv[ni] = bias[wc * 64 + ni * 16 + ml];

  const int gfirst = sbat[0];
  const int nspan = sbat[127] - gfirst + 1;
  if (nspan <= 4) {
    float* lred = (float*)&BsU[0][0];   // 32 KB dead LDS: [8 slots][4][256]
    const int slot = wr * 4 + q;
    for (int gl = 0; gl < nspan; gl++) {
#pragma unroll
      for (int ni = 0; ni < 4; ni++) {
        float s = 0.f;
#pragma unroll
        for (int mi = 0; mi < 4; mi++)
#pragma unroll
          for (int j = 0; j < 4; j++) {
            int row = i0 + wr * 64 + mi * 16 + q * 4 + j;
            if (row < M && sbat[row - i0] - gfirst == gl)
              s += fmaxf(acc[mi][ni][j] + bv[ni], 0.f);
          }
        lred[(slot * 4 + gl) * 256 + wc * 64 + ni * 16 + ml] = s;  // unique
      }
    }
    __syncthreads();
    for (int idx = tid; idx < nspan * 256; idx += 512) {
      int gl = idx >> 8, col = idx & 255;
      float s = 0.f;
#pragma unroll
      for (int sl = 0; sl < 8; sl++)
        s += lred[(sl * 4 + gl) * 256 + col];
      atomicAdd(&gsum[(size_t)(gfirst + gl) * D + col], s);
    }
  } else {
    // rare: >4 graphs in 128 rows — direct per-value atomics
#pragma unroll
    for (int mi = 0; mi < 4; mi++)
#pragma unroll
      for (int j = 0; j < 4; j++) {
        int row = i0 + wr * 64 + mi * 16 + q * 4 + j;
        if (row >= M) continue;
        int g = sbat[row - i0];
#pragma unroll
        for (int ni = 0; ni < 4; ni++) {
          int col = wc * 64 + ni * 16 + ml;
          atomicAdd(&gsum[(size_t)g * D + col],
                    fmaxf(acc[mi][ni][j] + bv[ni], 0.f));
        }
      }
  }
}

// ---------------- final: graph mean + linear head from gsum (r9-proven) ---
__global__ __launch_bounds__(64) void k_final(
    const float* __restrict__ gsum, const int* __restrict__ gstart,
    const float* __restrict__ linW, const float* __restrict__ linb,
    float* __restrict__ out, int G) {
  int g = blockIdx.x, lane = threadIdx.x;
  int cnt = gstart[g + 1] - gstart[g];
  float inv = (cnt > 0) ? 1.0f / (float)cnt : 0.0f;
  float4 s = *(const float4*)(gsum + (size_t)g * D + lane * 4);
  float m0 = s.x * inv, m1 = s.y * inv, m2 = s.z * inv, m3 = s.w * inv;
  float4 w0 = *(const float4*)(linW + (lane * 4 + 0) * 4);
  float4 w1 = *(const float4*)(linW + (lane * 4 + 1) * 4);
  float4 w2 = *(const float4*)(linW + (lane * 4 + 2) * 4);
  float4 w3 = *(const float4*)(linW + (lane * 4 + 3) * 4);
  float p0 = m0 * w0.x + m1 * w1.x + m2 * w2.x + m3 * w3.x;
  float p1 = m0 * w0.y + m1 * w1.y + m2 * w2.y + m3 * w3.y;
  float p2 = m0 * w0.z + m1 * w1.z + m2 * w2.z + m3 * w3.z;
  float p3 = m0 * w0.w + m1 * w1.w + m2 * w2.w + m3 * w3.w;
  for (int o = 32; o > 0; o >>= 1) {
    p0 += __shfl_down(p0, o, 64);
    p1 += __shfl_down(p1, o, 64);
    p2 += __shfl_down(p2, o, 64);
    p3 += __shfl_down(p3, o, 64);
  }
  if (lane == 0) {
    out[g * 4 + 0] = p0 + linb[0];
    out[g * 4 + 1] = p1 + linb[1];
    out[g * 4 + 2] = p2 + linb[2];
    out[g * 4 + 3] = p3 + linb[3];
  }
}

extern "C" void kernel_launch(void* const* d_in, const int* in_sizes, int n_in,
                              void* d_out, int out_size, void* d_ws, size_t ws_size,
                              hipStream_t stream) {
  const int*   x     = (const int*)d_in[0];
  const int*   ei    = (const int*)d_in[1];
  const int*   et    = (const int*)d_in[2];
  const int*   batch = (const int*)d_in[3];
  const float* table = (const float*)d_in[5];
  const float* W1    = (const float*)d_in[6];
  const float* root1 = (const float*)d_in[7];
  const float* b1    = (const float*)d_in[8];
  const float* W2    = (const float*)d_in[9];
  const float* root2 = (const float*)d_in[10];
  const float* b2    = (const float*)d_in[11];
  const float* linW  = (const float*)d_in[12];
  const float* linb  = (const float*)d_in[13];
  float* out = (float*)d_out;

  const int N = in_sizes[0];
  const int E = in_sizes[2];
  const int G = out_size / 4;
  const int VOC = in_sizes[5] / D;
  const int* src = ei;
  const int* dst = ei + E;
  const int RN = 3 * N;

  // ---- ws layout, page aliasing proven rounds 5-17 ----
  char* wsb = (char*)d_ws;
  size_t pg = (size_t)N * D * 2;
  unsigned short* P0 = (unsigned short*)wsb;
  unsigned short* P1 = (unsigned short*)(wsb + pg);
  unsigned short* P3 = (unsigned short*)(wsb + 3 * pg);
  unsigned short* wb = (unsigned short*)(wsb + 4 * pg);  // 2 layers x 4 mats
  unsigned short* zrow = wb + 2 * 4 * 65536;   // 256 shorts (512 B zero row)
  int*   off    = (int*)(zrow + 256);
  int*   esx    = off + (RN + 1);       // L1 row ids (= x[src])
  int*   ess    = esx + E;              // L2 row ids (= src)
  int*   gstart = ess + E;
  unsigned short* tableb = P3;          // alias (dead after k_tgemm)
  unsigned short* Tbuf = P1;            // 20 MB in page1; dead before L2 agg
  int* cur  = (int*)P0;                 // alias (dead before combine writes P0)
  int* bsum = cur + RN;                 // alias
  // gsum aliases esx (dead after k_combine); 16B-align for float4
  float* gsum = (float*)((((size_t)esx) + 15) & ~(size_t)15);

  const int nb = (RN + SB - 1) / SB;

  // ---- setup: one fused kernel for all independent prep ----
  int nbZero = (RN + 1023) / 1024;
  int nbBounds = (N + 255) / 256;
  int nbCvt = (VOC * D / 8 + 255) / 256;     // x8 vectorized table cvt
  int g0 = nbZero, g1 = g0 + nbBounds, g2 = g1 + nbCvt, g3 = g2 + 256;
  k_setup<<<g3 + 256, 256, 0, stream>>>(cur, RN, batch, gstart, N, G,
      table, tableb, VOC * D, root1, W1, root2, W2, wb, (int*)zrow,
      g0, g1, g2, g3);

  // T depends only on setup — run before the CSR chain
  const int nbm = (VOC + 127) / 128;
  k_tgemm<<<nbm * 4, 512, 0, stream>>>(tableb, wb, Tbuf, VOC, nbm);

  k_count_i<<<(E + 255) / 256, 256, 0, stream>>>(dst, et, cur, E, N);
  k_scan1<<<nb, 256, 0, stream>>>(cur, bsum, RN);
  k_scan2<<<1, 256, 0, stream>>>(bsum, nb, off + RN);
  k_scan3<<<nb, 256, 0, stream>>>(cur, bsum, off, cur, RN);
  k_place2<<<(E + 255) / 256, 256, 0, stream>>>(src, dst, et, x, cur, esx, ess, E, N);

  // ---- layer 1 (algebraic): combine gathers from T ----
  k_combine<<<(N + 7) / 8, 256, 0, stream>>>(x, esx, off, Tbuf, b1, P0, N, VOC);

  // esx dead from here; zero the graph-sum buffer that aliases it
  k_zerog<<<(G * D / 4 + 255) / 256, 256, 0, stream>>>(gsum, G * D / 4);

  const int gagg = (RN + 31) / 32;      // 8 ids/wave x 4 waves
  const int ggemm = (N + 127) / 128;

  // ---- layer 2: agg + pooled GEMM (dedicated kernel, no C write) ----
  k_agg<<<gagg, 256, 0, stream>>>(P0, ess, off, P1, RN);
  k_lgemmP<<<ggemm, 512, 0, stream>>>(P0, P1, ess, off, zrow,
                                      wb + 4 * 65536, b2, batch, gsum, N, N);

  // ---- mean + linear head ----
  k_final<<<G, 64, 0, stream>>>(gsum, gstart, linW, linb, out, G);
}